// Round 16
// baseline (117.230 us; speedup 1.0000x reference)
//
#include <hip/hip_runtime.h>
#include <hip/hip_bf16.h>

#define D_MODEL 1024
#define SEQ     2048
#define NH      16
#define HD      64
#define M_TOK   4096
#define THREE_D 3072

using bf16x8 = __bf16 __attribute__((ext_vector_type(8)));
using bf16x4 = __bf16 __attribute__((ext_vector_type(4)));
using f32x4  = float  __attribute__((ext_vector_type(4)));

typedef __attribute__((address_space(3))) uint32_t lds_u32;
typedef const __attribute__((address_space(1))) uint32_t glb_u32;

// ---------------- cast fp32 -> bf16 (vectorized) ----------------
__global__ __launch_bounds__(256) void cast_kernel(const float* __restrict__ in,
                                                   __bf16* __restrict__ out, int n4) {
  int i = blockIdx.x * 256 + threadIdx.x;
  if (i < n4) {
    float4 f = reinterpret_cast<const float4*>(in)[i];
    bf16x4 o;
    o[0] = (__bf16)f.x; o[1] = (__bf16)f.y; o[2] = (__bf16)f.z; o[3] = (__bf16)f.w;
    reinterpret_cast<bf16x4*>(out)[i] = o;
  }
}

// ---------------- transpose + cast: in [R][C] f32 -> out [C][R] bf16 ----------------
__global__ __launch_bounds__(256) void transpose_cast(const float* __restrict__ in,
                                                      __bf16* __restrict__ out, int R, int C) {
  __shared__ float tile[64][65];
  int c0 = blockIdx.x * 64, r0 = blockIdx.y * 64;
  int tx = threadIdx.x & 63, ty = threadIdx.x >> 6;
#pragma unroll
  for (int i = 0; i < 16; ++i) {
    int r = ty + i * 4;
    tile[r][tx] = in[(size_t)(r0 + r) * C + c0 + tx];
  }
  __syncthreads();
#pragma unroll
  for (int i = 0; i < 16; ++i) {
    int r = ty + i * 4;
    out[(size_t)(c0 + r) * R + r0 + tx] = (__bf16)tile[tx][r];
  }
}

// ---------------- QKV GEMM: 128x128, BK=32, 3-deep pipeline, vectorized V scatter ----------------
// (R14-exact, measured best.) Q scaled 0.125 [bh][s][d]; K [bh][s][d]; V transposed [bh][d][s].
__global__ __launch_bounds__(256, 3) void gemm_qkv(const __bf16* __restrict__ A,
                                                   const __bf16* __restrict__ BT,
                                                   const float* __restrict__ bias,
                                                   __bf16* __restrict__ qb, __bf16* __restrict__ kb,
                                                   __bf16* __restrict__ vb) {
  __shared__ __bf16 As[3][128 * 32];
  __shared__ __bf16 Bs[3][128 * 32];
  const int Kdim = D_MODEL;
  const int tid  = threadIdx.x;
  const int lane = tid & 63, wave = tid >> 6;
  const int lr = lane & 15, lg = lane >> 4;
  const int wm = (wave >> 1) * 64, wn = (wave & 1) * 64;

  const int f   = blockIdx.x;
  const int swz = (f & 7) * 96 + (f >> 3);
  const int m0  = (swz / 24) * 128, n0 = (swz % 24) * 128;

  const int srow = tid >> 2, scol = (tid & 3) * 8;

  f32x4 acc[4][4] = {};

  const __bf16* aSrc = A  + (size_t)(m0 + srow) * Kdim + scol;
  const __bf16* bSrc = BT + (size_t)(n0 + srow) * Kdim + scol;

  auto stage = [&](int p, int k0) {
    __builtin_amdgcn_global_load_lds((glb_u32*)(aSrc + k0),              (lds_u32*)(As[p] + wave * 512),        16, 0, 0);
    __builtin_amdgcn_global_load_lds((glb_u32*)(aSrc + 64 * Kdim + k0), (lds_u32*)(As[p] + wave * 512 + 2048), 16, 0, 0);
    __builtin_amdgcn_global_load_lds((glb_u32*)(bSrc + k0),              (lds_u32*)(Bs[p] + wave * 512),        16, 0, 0);
    __builtin_amdgcn_global_load_lds((glb_u32*)(bSrc + 64 * Kdim + k0), (lds_u32*)(Bs[p] + wave * 512 + 2048), 16, 0, 0);
  };

  const int nk = Kdim / 32;
  stage(0, 0);
  stage(1, 32);
  for (int kk = 0; kk < nk; ++kk) {
    const int cur = kk % 3;
    if (kk + 2 < nk) {
      stage((kk + 2) % 3, (kk + 2) * 32);
      asm volatile("s_waitcnt vmcnt(8)" ::: "memory");
    } else if (kk + 1 < nk) {
      asm volatile("s_waitcnt vmcnt(4)" ::: "memory");
    } else {
      asm volatile("s_waitcnt vmcnt(0)" ::: "memory");
    }
    __builtin_amdgcn_s_barrier();

    bf16x8 af[4], bfv[4];
#pragma unroll
    for (int i = 0; i < 4; ++i) af[i]  = *reinterpret_cast<const bf16x8*>(&As[cur][(wm + i * 16 + lr) * 32 + lg * 8]);
#pragma unroll
    for (int j = 0; j < 4; ++j) bfv[j] = *reinterpret_cast<const bf16x8*>(&Bs[cur][(wn + j * 16 + lr) * 32 + lg * 8]);
#pragma unroll
    for (int i = 0; i < 4; ++i)
#pragma unroll
      for (int j = 0; j < 4; ++j)
        acc[i][j] = __builtin_amdgcn_mfma_f32_16x16x32_bf16(af[i], bfv[j], acc[i][j], 0, 0, 0);

    asm volatile("s_waitcnt lgkmcnt(0)" ::: "memory");
    __builtin_amdgcn_s_barrier();
  }

  const int reg = n0 >> 10;
  if (reg == 2) {
#pragma unroll
    for (int j = 0; j < 4; ++j) {
      const int gc = n0 + wn + j * 16 + lr;
      const float bv = bias[gc];
      const int rem = gc & 1023, h = rem >> 6, d = rem & 63;
#pragma unroll
      for (int i = 0; i < 4; ++i) {
        const int gr0 = m0 + wm + i * 16 + lg * 4;
        const int b = gr0 >> 11, s0 = gr0 & 2047;
        bf16x4 v4;
#pragma unroll
        for (int ii = 0; ii < 4; ++ii) v4[ii] = (__bf16)(acc[i][j][ii] + bv);
        *reinterpret_cast<bf16x4*>(&vb[(((size_t)(b * NH + h)) * HD + d) * SEQ + s0]) = v4;
      }
    }
  } else {
#pragma unroll
    for (int i = 0; i < 4; ++i) {
#pragma unroll
      for (int j = 0; j < 4; ++j) {
        const int gc = n0 + wn + j * 16 + lr;
        const float bv = bias[gc];
        const int rem = gc & 1023, h = rem >> 6, d = rem & 63;
#pragma unroll
        for (int ii = 0; ii < 4; ++ii) {
          const int gr = m0 + wm + i * 16 + lg * 4 + ii;
          const float val = acc[i][j][ii] + bv;
          const int b = gr >> 11, s = gr & 2047;
          if (reg == 0) qb[(((size_t)(b * NH + h)) * SEQ + s) * HD + d] = (__bf16)(val * 0.125f);
          else          kb[(((size_t)(b * NH + h)) * SEQ + s) * HD + d] = (__bf16)val;
        }
      }
    }
  }
}

// ---------------- proj GEMM: 64x128 tile, BK=32, 3-deep pipeline (R14-exact) ----------------
__global__ __launch_bounds__(256, 4) void gemm_proj(const __bf16* __restrict__ A,
                                                    const __bf16* __restrict__ BT,
                                                    const float* __restrict__ bias,
                                                    float* __restrict__ fout) {
  __shared__ __bf16 As[3][64 * 32];
  __shared__ __bf16 Bs[3][128 * 32];
  const int Kdim = D_MODEL;
  const int tid  = threadIdx.x;
  const int lane = tid & 63, wave = tid >> 6;
  const int lr = lane & 15, lg = lane >> 4;
  const int wm = (wave >> 1) * 32, wn = (wave & 1) * 64;
  const int n0 = blockIdx.x * 128, m0 = blockIdx.y * 64;
  const int srow = tid >> 2, scol = (tid & 3) * 8;

  f32x4 acc[2][4] = {};

  const __bf16* aSrc = A  + (size_t)(m0 + srow) * Kdim + scol;
  const __bf16* bSrc = BT + (size_t)(n0 + srow) * Kdim + scol;

  auto stage = [&](int p, int k0) {
    __builtin_amdgcn_global_load_lds((glb_u32*)(aSrc + k0),              (lds_u32*)(As[p] + wave * 512),        16, 0, 0);
    __builtin_amdgcn_global_load_lds((glb_u32*)(bSrc + k0),              (lds_u32*)(Bs[p] + wave * 512),        16, 0, 0);
    __builtin_amdgcn_global_load_lds((glb_u32*)(bSrc + 64 * Kdim + k0), (lds_u32*)(Bs[p] + wave * 512 + 2048), 16, 0, 0);
  };

  const int nk = Kdim / 32;
  stage(0, 0);
  stage(1, 32);
  for (int kk = 0; kk < nk; ++kk) {
    const int cur = kk % 3;
    if (kk + 2 < nk) {
      stage((kk + 2) % 3, (kk + 2) * 32);
      asm volatile("s_waitcnt vmcnt(6)" ::: "memory");
    } else if (kk + 1 < nk) {
      asm volatile("s_waitcnt vmcnt(3)" ::: "memory");
    } else {
      asm volatile("s_waitcnt vmcnt(0)" ::: "memory");
    }
    __builtin_amdgcn_s_barrier();

    bf16x8 af[2], bfv[4];
#pragma unroll
    for (int i = 0; i < 2; ++i) af[i]  = *reinterpret_cast<const bf16x8*>(&As[cur][(wm + i * 16 + lr) * 32 + lg * 8]);
#pragma unroll
    for (int j = 0; j < 4; ++j) bfv[j] = *reinterpret_cast<const bf16x8*>(&Bs[cur][(wn + j * 16 + lr) * 32 + lg * 8]);
#pragma unroll
    for (int i = 0; i < 2; ++i)
#pragma unroll
      for (int j = 0; j < 4; ++j)
        acc[i][j] = __builtin_amdgcn_mfma_f32_16x16x32_bf16(af[i], bfv[j], acc[i][j], 0, 0, 0);

    asm volatile("s_waitcnt lgkmcnt(0)" ::: "memory");
    __builtin_amdgcn_s_barrier();
  }

#pragma unroll
  for (int i = 0; i < 2; ++i) {
#pragma unroll
    for (int j = 0; j < 4; ++j) {
      const int gc = n0 + wn + j * 16 + lr;
      const float bv = bias[gc];
#pragma unroll
      for (int ii = 0; ii < 4; ++ii) {
        const int gr = m0 + wm + i * 16 + lg * 4 + ii;
        fout[(size_t)gr * D_MODEL + gc] = acc[i][j][ii] + bv;
      }
    }
  }
}

// ---------------- attn stage 1: split-K partials ----------------
// Unit = (bh, q-block of 64 rows, key-slice of <=8 tiles). 2560 blocks.
// Writes partial O (bf16) and partial l (f32); no-max softmax -> partials sum exactly.
__global__ __launch_bounds__(256, 4) void attn_part(const __bf16* __restrict__ Q,
                                                    const __bf16* __restrict__ K,
                                                    const __bf16* __restrict__ VT,
                                                    __bf16* __restrict__ po,
                                                    float* __restrict__ pl) {
  __shared__ __bf16 Kb[2][64 * 64];
  __shared__ __bf16 Vb[2][64 * 64];
  __shared__ __bf16 Ps[4][16 * 64];

  const int tid  = threadIdx.x;
  const int lane = tid & 63, wave = tid >> 6;
  const int lr = lane & 15, lg = lane >> 4;

  // decode: XCD residue groups 4 heads; u -> (q, slice)
  const int f  = blockIdx.x;
  const int c  = f & 7;
  const int g  = f >> 3;
  const int bh = c * 4 + (g & 3);
  const int u  = g >> 2;                 // 0..79
  int q, s;
  if (u < 8)       { q = u;              s = 0; }
  else if (u < 24) { int v = u - 8;  q = 8 + (v >> 1);  s = v & 1; }
  else if (u < 48) { int v = u - 24; q = 16 + v / 3;    s = v % 3; }
  else             { int v = u - 48; q = 24 + (v >> 2); s = v & 3; }

  const int t0 = s * 8;
  const int t1 = min(s * 8 + 8, q + 1);

  const int q0 = q * 64 + wave * 16;
  const size_t base = (size_t)bh * SEQ * HD;
  const char* Kg  = (const char*)(K + base);
  const char* VTg = (const char*)(VT + base);

  bf16x8 qf[2];
#pragma unroll
  for (int kc = 0; kc < 2; ++kc)
    qf[kc] = *reinterpret_cast<const bf16x8*>(Q + base + (size_t)(q0 + lr) * HD + kc * 32 + lg * 8);

  float lrun[4] = {0.f, 0.f, 0.f, 0.f};
  f32x4 o[4] = {};

  const int nmaxF = (wave | 1) + 1;

  auto stage = [&](int bufp, int t) {
    const int k0 = t * 64;
#pragma unroll
    for (int p = 0; p < 2; ++p) {
      const int row = wave * 16 + p * 8 + (lane >> 3);
      {
        const int srcOff = (k0 + row) * 128 + (((lane & 7) ^ (row & 7)) << 4);
        __builtin_amdgcn_global_load_lds((glb_u32*)(Kg + srcOff),
                                         (lds_u32*)&Kb[bufp][(wave * 16 + p * 8) * 64], 16, 0, 0);
      }
      {
        const int srcOff = row * 4096 + k0 * 2 + (((lane & 7) ^ (row & 7)) << 4);
        __builtin_amdgcn_global_load_lds((glb_u32*)(VTg + srcOff),
                                         (lds_u32*)&Vb[bufp][(wave * 16 + p * 8) * 64], 16, 0, 0);
      }
    }
  };

  stage(0, t0);
  asm volatile("s_waitcnt vmcnt(0)" ::: "memory");
  __syncthreads();

  for (int t = t0; t < t1; ++t) {
    const int p = (t - t0) & 1;
    const int k0 = t * 64;
    const bool diag = (t == q);
    const int nmax = diag ? nmaxF : 4;
    const int kcmax = nmax >> 1;

    if (t + 1 < t1) stage(p ^ 1, t + 1);

    const __bf16* Kt = Kb[p];
    const __bf16* Vt = Vb[p];

    f32x4 sc[4] = {};
#pragma unroll
    for (int kc = 0; kc < 2; ++kc) {
#pragma unroll
      for (int n = 0; n < 4; ++n)
        if (n < nmax) {
          bf16x8 kf = *reinterpret_cast<const bf16x8*>(
              &Kt[(n * 16 + lr) * 64 + (((kc * 4 + lg) ^ (lr & 7)) << 3)]);
          sc[n] = __builtin_amdgcn_mfma_f32_16x16x32_bf16(qf[kc], kf, sc[n], 0, 0, 0);
        }
    }

    if (diag) {
#pragma unroll
      for (int n = 0; n < 4; ++n)
        if (n < nmax)
#pragma unroll
          for (int ii = 0; ii < 4; ++ii) {
            int qg = q0 + lg * 4 + ii;
            int kg = k0 + n * 16 + lr;
            if (kg > qg) sc[n][ii] = -__builtin_inff();
          }
    }

#pragma unroll
    for (int n = 0; n < 4; ++n)
      if (n < nmax)
#pragma unroll
        for (int ii = 0; ii < 4; ++ii) {
          float pv = __expf(sc[n][ii]);
          lrun[ii] += pv;
          const int row = lg * 4 + ii;
          Ps[wave][row * 64 + (((n * 2 + (lr >> 3)) ^ (row & 7)) << 3) + (lr & 7)] = (__bf16)pv;
        }

#pragma unroll
    for (int kc = 0; kc < 2; ++kc)
      if (kc < kcmax) {
        bf16x8 pa = *reinterpret_cast<const bf16x8*>(
            &Ps[wave][lr * 64 + (((kc * 4 + lg) ^ (lr & 7)) << 3)]);
#pragma unroll
        for (int nd = 0; nd < 4; ++nd) {
          bf16x8 vf = *reinterpret_cast<const bf16x8*>(
              &Vt[(nd * 16 + lr) * 64 + (((kc * 4 + lg) ^ (lr & 7)) << 3)]);
          o[nd] = __builtin_amdgcn_mfma_f32_16x16x32_bf16(pa, vf, o[nd], 0, 0, 0);
        }
      }

    asm volatile("s_waitcnt vmcnt(0)" ::: "memory");
    __syncthreads();
  }

  // row-sum reduce within 16-lane groups (bits 0-3 of lane)
#pragma unroll
  for (int off = 1; off <= 8; off <<= 1)
#pragma unroll
    for (int ii = 0; ii < 4; ++ii) lrun[ii] += __shfl_xor(lrun[ii], off, 64);

  // write partials
  const int slot = (bh * 32 + q) * 4 + s;
  __bf16* poPtr = po + (size_t)slot * 64 * 64;
  if (lr == 0) {
#pragma unroll
    for (int ii = 0; ii < 4; ++ii)
      pl[(size_t)slot * 64 + wave * 16 + lg * 4 + ii] = lrun[ii];
  }
#pragma unroll
  for (int nd = 0; nd < 4; ++nd)
#pragma unroll
    for (int ii = 0; ii < 4; ++ii) {
      const int row = wave * 16 + lg * 4 + ii;
      poPtr[(size_t)row * 64 + nd * 16 + lr] = (__bf16)o[nd][ii];
    }
}

// ---------------- attn stage 2: merge slices, normalize, write ao ----------------
__global__ __launch_bounds__(256) void attn_merge(const __bf16* __restrict__ po,
                                                  const float* __restrict__ pl,
                                                  __bf16* __restrict__ AO) {
  const int blk = blockIdx.x;          // bh*32 + q
  const int bh = blk >> 5, q = blk & 31;
  const int ns = (q >> 3) + 1;
  const int tid = threadIdx.x;
  const int row = tid >> 2;
  const int d0  = (tid & 3) * 16;
  const size_t sbase = (size_t)blk * 4;

  float acc[16] = {};
  float lsum = 0.f;
  for (int s = 0; s < ns; ++s) {
    const __bf16* pr = po + ((sbase + s) * 64 + row) * 64 + d0;
    bf16x8 a = *reinterpret_cast<const bf16x8*>(pr);
    bf16x8 b = *reinterpret_cast<const bf16x8*>(pr + 8);
#pragma unroll
    for (int j = 0; j < 8; ++j) { acc[j] += (float)a[j]; acc[8 + j] += (float)b[j]; }
    lsum += pl[(sbase + s) * 64 + row];
  }
  const float r = 1.f / lsum;
  const int b_ = bh >> 4, h = bh & 15;
  const int grow = q * 64 + row;
  bf16x8 o1, o2;
#pragma unroll
  for (int j = 0; j < 8; ++j) { o1[j] = (__bf16)(acc[j] * r); o2[j] = (__bf16)(acc[8 + j] * r); }
  __bf16* dst = AO + ((size_t)(b_ * SEQ) + grow) * D_MODEL + h * HD + d0;
  *reinterpret_cast<bf16x8*>(dst)     = o1;
  *reinterpret_cast<bf16x8*>(dst + 8) = o2;
}

// ---------------- launch ----------------
extern "C" void kernel_launch(void* const* d_in, const int* in_sizes, int n_in,
                              void* d_out, int out_size, void* d_ws, size_t ws_size,
                              hipStream_t stream) {
  const float* x      = (const float*)d_in[0];
  const float* w_qkv  = (const float*)d_in[1];
  const float* b_qkv  = (const float*)d_in[2];
  const float* w_proj = (const float*)d_in[3];
  const float* b_proj = (const float*)d_in[4];
  float* out = (float*)d_out;

  char* ws = (char*)d_ws;
  __bf16* xb     = (__bf16*)(ws);                    // 8 MiB
  __bf16* wqkvT  = (__bf16*)(ws + 8388608);          // 6 MiB
  __bf16* wprojT = (__bf16*)(ws + 14680064);         // 2 MiB
  __bf16* qb     = (__bf16*)(ws + 16777216);         // 8 MiB
  __bf16* kb     = (__bf16*)(ws + 25165824);         // 8 MiB
  __bf16* vtb    = (__bf16*)(ws + 33554432);         // 8 MiB (transposed V)
  __bf16* ao     = (__bf16*)(ws + 41943040);         // 8 MiB  (ends 48 MiB)
  __bf16* po     = (__bf16*)(ws + 50331648);         // 32 MiB partial O (48..80)
  float*  pl     = (float*)(ws + 83886080);          // 1 MiB partial l  (80..81)

  cast_kernel<<<4096, 256, 0, stream>>>(x, xb, M_TOK * D_MODEL / 4);
  transpose_cast<<<dim3(THREE_D / 64, D_MODEL / 64), 256, 0, stream>>>(w_qkv, wqkvT, D_MODEL, THREE_D);
  transpose_cast<<<dim3(D_MODEL / 64, D_MODEL / 64), 256, 0, stream>>>(w_proj, wprojT, D_MODEL, D_MODEL);

  gemm_qkv<<<768, 256, 0, stream>>>(xb, wqkvT, b_qkv, qb, kb, vtb);

  attn_part<<<2560, 256, 0, stream>>>(qb, kb, vtb, po, pl);
  attn_merge<<<1024, 256, 0, stream>>>(po, pl, ao);

  gemm_proj<<<dim3(D_MODEL / 128, M_TOK / 64), 256, 0, stream>>>(
      ao, wprojT, b_proj, out);
}